// Round 12
// baseline (101.511 us; speedup 1.0000x reference)
//
#include <hip/hip_runtime.h>
#include <hip/hip_bf16.h>

#define BQ 4
#define LQ 4096
#define DM 512
#define DK 64
#define NROWS (BQ * DK)        // 256
#define TOPK 16
#define CAND 32

typedef __attribute__((ext_vector_type(8))) short short8v;
typedef __attribute__((ext_vector_type(16))) float f32x16;

__device__ __forceinline__ unsigned short f2bf(float x) {
  unsigned u = __builtin_bit_cast(unsigned, x);
  return (unsigned short)((u + 0x7FFFu + ((u >> 16) & 1u)) >> 16);
}
__device__ __forceinline__ float bf2f(unsigned short h) {
  unsigned u = ((unsigned)h) << 16;
  return __builtin_bit_cast(float, u);
}

// MFMA->VALU drain (epilogue): nothing crosses; 32 wait cycles.
__device__ __forceinline__ void mfma_drain() {
  __builtin_amdgcn_sched_barrier(0);
  asm volatile("s_nop 7\n\ts_nop 7\n\ts_nop 7\n\ts_nop 7" ::: "memory");
  __builtin_amdgcn_sched_barrier(0);
}

// ---------------------------------------------------------------------------
// Kernel 0: precompute W^T hi/lo bf16 in B-fragment layout. grid 8, block 256.
// ---------------------------------------------------------------------------
__global__ __launch_bounds__(256) void wprep_kernel(
    const float* __restrict__ Wq, short* __restrict__ whT,
    short* __restrict__ wlT) {
  __shared__ short lh[64][66];
  __shared__ short ll[64][66];
  const int tid = threadIdx.x;
  const int k0 = blockIdx.x * 64;
#pragma unroll
  for (int p = 0; p < 16; ++p) {
    int idx = p * 256 + tid;
    int kr = idx >> 6, j = idx & 63;
    float v = Wq[(size_t)(k0 + kr) * DK + j];
    unsigned short h = f2bf(v);
    lh[j][kr] = (short)h;
    ll[j][kr] = (short)f2bf(v - bf2f(h));
  }
  __syncthreads();
  const int j = tid >> 2, ks = (tid & 3) * 16;
  short8v o0, o1;
#pragma unroll
  for (int i = 0; i < 8; ++i) { o0[i] = lh[j][ks + i]; o1[i] = lh[j][ks + 8 + i]; }
  *(short8v*)(&whT[(size_t)j * DM + k0 + ks]) = o0;
  *(short8v*)(&whT[(size_t)j * DM + k0 + ks + 8]) = o1;
#pragma unroll
  for (int i = 0; i < 8; ++i) { o0[i] = ll[j][ks + i]; o1[i] = ll[j][ks + 8 + i]; }
  *(short8v*)(&wlT[(size_t)j * DM + k0 + ks]) = o0;
  *(short8v*)(&wlT[(size_t)j * DM + k0 + ks + 8]) = o1;
}

// ---------------------------------------------------------------------------
// Kernel 1 v4c: barrier-free split-bf16 MFMA projection with FULL hazard
// fencing for VALU-sourced operands: each s-step's 6 MFMAs live in ONE asm
// block; leading s_nop 4 covers VALU-write->MFMA-read (RAW), trailing
// s_nop 7 + s_nop 3 cover MFMA-source-read->VALU-overwrite (WAR, 8-pass).
// ---------------------------------------------------------------------------
__global__ __launch_bounds__(256) void proj_kernel(
    const float* __restrict__ q_in, const float* __restrict__ k_in,
    const float* __restrict__ v_in, const short* __restrict__ whT,
    const short* __restrict__ wlT, const float* __restrict__ bq,
    float* __restrict__ ws) {
  const float* x = blockIdx.z == 0 ? q_in : (blockIdx.z == 1 ? k_in : v_in);
  float* outp = ws + (size_t)blockIdx.z * (size_t)(NROWS * LQ);

  __shared__ __align__(16) float ts[8 * 1088];   // epilogue scratch

  const int tid = threadIdx.x;
  const int l = tid & 63, wv = tid >> 6;
  const int gw = blockIdx.x * 4 + wv;            // 0..511
  const int R0 = gw * 32;
  const int koff = 8 * (l >> 5);

  const float* xb = x + (size_t)(R0 + (l & 31)) * DM + koff;
  const short* bh0p = whT + (size_t)(l & 31) * DM + koff;
  const short* bl0p = wlT + (size_t)(l & 31) * DM + koff;
  const short* bh1p = whT + (size_t)(32 + (l & 31)) * DM + koff;
  const short* bl1p = wlT + (size_t)(32 + (l & 31)) * DM + koff;

  f32x16 acc[2];
#pragma unroll
  for (int nt = 0; nt < 2; ++nt)
#pragma unroll
    for (int i = 0; i < 16; ++i) acc[nt][i] = 0.f;

  float4 a0[8], a1[8];
#pragma unroll
  for (int s = 0; s < 4; ++s) {
    a0[2 * s]     = *(const float4*)(xb + s * 16);
    a0[2 * s + 1] = *(const float4*)(xb + s * 16 + 4);
  }

#pragma unroll
  for (int kb = 0; kb < 8; ++kb) {
    if (kb < 7) {
#pragma unroll
      for (int s = 0; s < 4; ++s) {
        a1[2 * s]     = *(const float4*)(xb + (kb + 1) * 64 + s * 16);
        a1[2 * s + 1] = *(const float4*)(xb + (kb + 1) * 64 + s * 16 + 4);
      }
    }
#pragma unroll
    for (int s = 0; s < 4; ++s) {
      float f[8] = {a0[2 * s].x, a0[2 * s].y, a0[2 * s].z, a0[2 * s].w,
                    a0[2 * s + 1].x, a0[2 * s + 1].y, a0[2 * s + 1].z,
                    a0[2 * s + 1].w};
      short8v ah, al;
#pragma unroll
      for (int i = 0; i < 8; ++i) {
        unsigned short h = f2bf(f[i]);
        ah[i] = (short)h;
        al[i] = (short)f2bf(f[i] - bf2f(h));
      }
      const int ko = kb * 64 + s * 16;
      short8v bh0 = *(const short8v*)(bh0p + ko);
      short8v bl0 = *(const short8v*)(bl0p + ko);
      short8v bh1 = *(const short8v*)(bh1p + ko);
      short8v bl1 = *(const short8v*)(bl1p + ko);
      asm volatile(
          "s_nop 4\n\t"
          "v_mfma_f32_32x32x16_bf16 %0, %2, %4, %0\n\t"
          "v_mfma_f32_32x32x16_bf16 %0, %2, %5, %0\n\t"
          "v_mfma_f32_32x32x16_bf16 %0, %3, %4, %0\n\t"
          "v_mfma_f32_32x32x16_bf16 %1, %2, %6, %1\n\t"
          "v_mfma_f32_32x32x16_bf16 %1, %2, %7, %1\n\t"
          "v_mfma_f32_32x32x16_bf16 %1, %3, %6, %1\n\t"
          "s_nop 7\n\t"
          "s_nop 3"
          : "+v"(acc[0]), "+v"(acc[1])
          : "v"(ah), "v"(al), "v"(bh0), "v"(bl0), "v"(bh1), "v"(bl1));
    }
    if (kb < 7) {
#pragma unroll
      for (int i = 0; i < 8; ++i) a0[i] = a1[i];
    }
  }

  // ---- epilogue: drain, bias + per-wave LDS transpose + stores ----
  mfma_drain();
  const int b = R0 >> 12, i0 = R0 & (LQ - 1);
  float bb[2] = {bq[l & 31], bq[32 + (l & 31)]};
#pragma unroll
  for (int nt = 0; nt < 2; ++nt) {
    float* area = ts + (wv * 2 + nt) * 1088;
#pragma unroll
    for (int r = 0; r < 16; ++r) {
      int io = (r & 3) + 8 * (r >> 2) + 4 * (l >> 5);
      area[(l & 31) * 34 + io] = acc[nt][r] + bb[nt];
    }
  }
  __syncthreads();
  const int e = l & 15, jg = l >> 4;
#pragma unroll
  for (int nt = 0; nt < 2; ++nt) {
    const float* area = ts + (wv * 2 + nt) * 1088;
#pragma unroll
    for (int p = 0; p < 8; ++p) {
      int jj = jg * 8 + p;
      float2 v = *reinterpret_cast<const float2*>(area + jj * 34 + e * 2);
      *reinterpret_cast<float2*>(
          &outp[((size_t)b * DK + nt * 32 + jj) * LQ + i0 + e * 2]) = v;
    }
  }
}

// ---------------------------------------------------------------------------
// Kernel 2 (r9-proven): fused corr+topk, 8 waves, scratch-free screen.
// (MFMA operands here are ds_read-sourced -> waitcnt interlocks; unchanged.)
// ---------------------------------------------------------------------------
__global__ __launch_bounds__(512) void corr_topk_kernel(
    const float* __restrict__ qp, const float* __restrict__ kp,
    float* __restrict__ lw) {
  const int row = blockIdx.x;
  const int tid = threadIdx.x;
  __shared__ __align__(16) short qs[3 * 4112 + 4096];  // 32864 B; red overlay
  __shared__ __align__(16) short ks[4096];             // 8192 B
  __shared__ __align__(16) float qf[LQ];               // fp32 for refine
  __shared__ __align__(16) float kf[LQ];
  __shared__ unsigned wk[128];
  __shared__ unsigned scand[CAND];
  __shared__ float rS[CAND];
  __shared__ float ordv[TOPK]; __shared__ int ordl[TOPK];

  const float* qr = qp + ((size_t)row << 12);
  const float* kr = kp + ((size_t)row << 12);

  {
    const float4* q4 = (const float4*)qr;
    float4 v0 = q4[tid * 2], v1 = q4[tid * 2 + 1];
    float4 v2 = q4[(tid * 2 + 2) & 1023];
    ((float4*)qf)[tid * 2] = v0;
    ((float4*)qf)[tid * 2 + 1] = v1;
    float f[12] = {v0.x, v0.y, v0.z, v0.w, v1.x, v1.y, v1.z, v1.w,
                   v2.x, v2.y, v2.z, v2.w};
#pragma unroll
    for (int r = 0; r < 4; ++r) {
      short8v o;
#pragma unroll
      for (int i = 0; i < 8; ++i) o[i] = (short)f2bf(f[i + r]);
      *(short8v*)(&qs[r * 4112 + tid * 8]) = o;
    }
    const float4* k4 = (const float4*)kr;
    float4 w0 = k4[tid * 2], w1 = k4[tid * 2 + 1];
    ((float4*)kf)[tid * 2] = w0;
    ((float4*)kf)[tid * 2 + 1] = w1;
    float g[8] = {w0.x, w0.y, w0.z, w0.w, w1.x, w1.y, w1.z, w1.w};
    int Q = tid;
    int Qs = Q ^ ((Q >> 3) & 7);
    short8v o;
#pragma unroll
    for (int i = 0; i < 8; ++i) o[i] = (short)f2bf(g[i]);
    *(short8v*)(&ks[Qs << 3]) = o;
  }
  __syncthreads();

  const int l = tid & 63, wv = tid >> 6;    // 8 waves
  const int Oq = ((8 * (l >> 5) - 32 * (l & 31)) & 4095) >> 3;
  const int rB = (l & 31) & 3;
  const int Ce = (l & 31) + 8 * (l >> 5) - rB;
  const short* qb = qs + rB * 4112;

  f32x16 acc[4];
#pragma unroll
  for (int M = 0; M < 4; ++M)
#pragma unroll
    for (int i = 0; i < 16; ++i) acc[M][i] = 0.f;

  const int J0 = wv * 32;
#pragma unroll 2
  for (int jb = 0; jb < 32; ++jb) {
    const int J = J0 + jb;
    int e1 = (Ce + 16 * J) & 4095;
    int e2 = (e1 + 4) & 4095;
    uint2 blo = *(const uint2*)(qb + e1);
    uint2 bhi = *(const uint2*)(qb + e2);
    int4 bi; bi.x = blo.x; bi.y = blo.y; bi.z = bhi.x; bi.w = bhi.y;
    short8v bf = __builtin_bit_cast(short8v, bi);
    const int Dq = 2 * J;
#pragma unroll
    for (int M = 0; M < 4; ++M) {
      int Q = (Oq + Dq - 128 * M) & 511;
      Q ^= (Q >> 3) & 7;
      short8v af = *(const short8v*)(&ks[Q << 3]);
      asm volatile("s_nop 4\n\t"
                   "v_mfma_f32_32x32x16_bf16 %0, %1, %2, %0\n\t"
                   "s_nop 7\n\t"
                   "s_nop 3"
                   : "+v"(acc[M]) : "v"(af), "v"(bf));
    }
  }

  mfma_drain();
  __syncthreads();
  float* red = (float*)qs;               // 2 strips x 4096 f32
  const int strip = (wv & 1) * 4096;
  const int ch4 = (l >> 5) * 4, cn = l & 31;
#define RIDX(M, r) (strip + ((M) << 10) + 32 * (((r)&3) + 8 * ((r) >> 2) + ch4) + cn)
  if (wv < 2) {
#pragma unroll
    for (int M = 0; M < 4; ++M)
#pragma unroll
      for (int r = 0; r < 16; ++r) red[RIDX(M, r)] = acc[M][r];
  }
  __syncthreads();
  if (wv >= 2 && wv < 4) {
#pragma unroll
    for (int M = 0; M < 4; ++M)
#pragma unroll
      for (int r = 0; r < 16; ++r) red[RIDX(M, r)] += acc[M][r];
  }
  __syncthreads();
  if (wv >= 4 && wv < 6) {
#pragma unroll
    for (int M = 0; M < 4; ++M)
#pragma unroll
      for (int r = 0; r < 16; ++r) red[RIDX(M, r)] += acc[M][r];
  }
  __syncthreads();
  if (wv >= 6) {
#pragma unroll
    for (int M = 0; M < 4; ++M)
#pragma unroll
      for (int r = 0; r < 16; ++r) red[RIDX(M, r)] += acc[M][r];
  }
  __syncthreads();
#undef RIDX

  {
    unsigned key[8];
#pragma unroll
    for (int i = 0; i < 8; ++i) {
      int tau = wv * 512 + i * 64 + l;
      float v = red[tau] + red[4096 + tau];
      unsigned u = __builtin_bit_cast(unsigned, fabsf(v));
      key[i] = (u & 0xFFFFF000u) | (unsigned)(4095 - tau);
    }
    unsigned bkey = key[0];
#pragma unroll
    for (int i = 1; i < 8; ++i) bkey = key[i] > bkey ? key[i] : bkey;
    for (int round = 0; round < 16; ++round) {
      unsigned m = bkey;
#pragma unroll
      for (int off = 1; off < 64; off <<= 1) {
        unsigned o = __shfl_xor(m, off);
        m = o > m ? o : m;
      }
      if (l == 0) wk[wv * 16 + round] = m;
#pragma unroll
      for (int i = 0; i < 8; ++i) key[i] = (key[i] == m) ? 0u : key[i];
      bkey = key[0];
#pragma unroll
      for (int i = 1; i < 8; ++i) bkey = key[i] > bkey ? key[i] : bkey;
    }
  }
  __syncthreads();

  if (tid < 128) {
    unsigned ki = wk[tid];
    int rank = 0;
    for (int j = 0; j < 128; ++j) rank += (wk[j] > ki);
    if (rank < CAND) scand[rank] = ki;
  }
  __syncthreads();

  {
    const int ci = tid >> 4, sub = tid & 15;
    const int lag = 4095 - (int)(scand[ci] & 0xFFFu);
    float S0 = 0.f, S1 = 0.f, S2 = 0.f, S3 = 0.f;
    for (int it = 0; it < 256; it += 4) {
      int t0 = (it + 0) * 16 + sub, t1 = (it + 1) * 16 + sub;
      int t2 = (it + 2) * 16 + sub, t3 = (it + 3) * 16 + sub;
      S0 = fmaf(kf[t0], qf[(t0 + lag) & 4095], S0);
      S1 = fmaf(kf[t1], qf[(t1 + lag) & 4095], S1);
      S2 = fmaf(kf[t2], qf[(t2 + lag) & 4095], S2);
      S3 = fmaf(kf[t3], qf[(t3 + lag) & 4095], S3);
    }
    float S = (S0 + S1) + (S2 + S3);
    S += __shfl_xor(S, 1);
    S += __shfl_xor(S, 2);
    S += __shfl_xor(S, 4);
    S += __shfl_xor(S, 8);
    if (sub == 0) rS[ci] = S;
  }
  __syncthreads();

  if (tid < CAND) {
    float vi = fabsf(rS[tid]);
    int ii = 4095 - (int)(scand[tid] & 0xFFFu);
    int rank = 0;
    for (int j = 0; j < CAND; ++j) {
      float vj = fabsf(rS[j]);
      int ij = 4095 - (int)(scand[j] & 0xFFFu);
      rank += (vj > vi) || (vj == vi && ij < ii);
    }
    if (rank < TOPK) { ordv[rank] = vi; ordl[rank] = ii; }
  }
  __syncthreads();

  if (tid == 0) {
    float m0 = ordv[0], s = 0.f, e[TOPK];
    for (int k = 0; k < TOPK; ++k) { e[k] = expf(ordv[k] - m0); s += e[k]; }
    float inv = 1.f / s;
    int* ip = (int*)(lw + (size_t)row * 32);
    for (int k = 0; k < TOPK; ++k) {
      ip[k] = ordl[k];
      ((float*)ip)[TOPK + k] = e[k] * inv;
    }
  }
}

// ---------------------------------------------------------------------------
// Kernel 4: aggregation  aggT[row][t] = sum_k w_k * v[row][(t+lag_k)%L]
// ---------------------------------------------------------------------------
__global__ void agg_kernel(const float* __restrict__ vpT,
                           const float* __restrict__ lw,
                           float* __restrict__ aggT) {
  const int row = blockIdx.x, tid = threadIdx.x;
  __shared__ __align__(16) float vr[2 * LQ];
  __shared__ float w[TOPK]; __shared__ int lg[TOPK];

  const float* v0 = vpT + (size_t)row * LQ;
  for (int x = tid; x < LQ; x += 256) {
    float val = v0[x];
    vr[x] = val; vr[x + LQ] = val;
  }
  if (tid < TOPK) {
    lg[tid] = ((const int*)(lw + (size_t)row * 32))[tid];
    w[tid] = lw[(size_t)row * 32 + TOPK + tid];
  }
  __syncthreads();

  float wr[TOPK]; int lr[TOPK];
#pragma unroll
  for (int k = 0; k < TOPK; ++k) { wr[k] = w[k]; lr[k] = lg[k]; }

  for (int m = 0; m < 16; ++m) {
    int t = m * 256 + tid;
    float a = 0.f;
#pragma unroll
    for (int k = 0; k < TOPK; ++k) a = fmaf(wr[k], vr[t + lr[k]], a);
    aggT[(size_t)row * LQ + t] = a;
  }
}

// ---------------------------------------------------------------------------
// Kernel 5: transpose + head-broadcast  out[b][t][c] = aggT[b][c&63][t]
// ---------------------------------------------------------------------------
__global__ void trans_kernel(const float* __restrict__ aggT,
                             float* __restrict__ out) {
  const int b = blockIdx.y;
  const int t0 = blockIdx.x * 64;
  const int tid = threadIdx.x;
  __shared__ float ts[64][65];

#pragma unroll
  for (int v = 0; v < 16; ++v) {
    int f = v * 256 + tid;
    int d = f >> 6, tt = f & 63;
    ts[d][tt] = aggT[((size_t)b * DK + d) * LQ + t0 + tt];
  }
  __syncthreads();

#pragma unroll
  for (int v = 0; v < 128; ++v) {
    int f = v * 256 + tid;
    int tt = f >> 9, c = f & 511;
    out[((size_t)b * LQ + t0 + tt) * (8 * DK) + c] = ts[c & 63][tt];
  }
}

// ---------------------------------------------------------------------------
// ws layout (floats): [0,1M) qp  [1M,2M) kp  [2M,3M) vp
//   [3M,+8K) lw  [4M,5M) aggT  [5M,+16K) whT  [5M+16K,+16K) wlT
// ---------------------------------------------------------------------------
extern "C" void kernel_launch(void* const* d_in, const int* in_sizes, int n_in,
                              void* d_out, int out_size, void* d_ws, size_t ws_size,
                              hipStream_t stream) {
  const float* q_in = (const float*)d_in[0];
  const float* k_in = (const float*)d_in[1];
  const float* v_in = (const float*)d_in[2];
  const float* Wq   = (const float*)d_in[3];
  const float* bq   = (const float*)d_in[4];
  float* out = (float*)d_out;
  float* ws  = (float*)d_ws;

  const size_t M = (size_t)NROWS * LQ;        // 1,048,576 floats
  float* qp   = ws;
  float* kp   = ws + M;
  float* vp   = ws + 2 * M;
  float* lw   = ws + 3 * M;
  float* aggT = ws + 4 * M;
  short* whT  = (short*)(ws + 5 * M);
  short* wlT  = (short*)(ws + 5 * M + 16384);

  wprep_kernel<<<8, 256, 0, stream>>>(Wq, whT, wlT);
  proj_kernel<<<dim3(128, 1, 3), 256, 0, stream>>>(q_in, k_in, v_in, whT, wlT,
                                                   bq, ws);
  corr_topk_kernel<<<NROWS, 512, 0, stream>>>(qp, kp, lw);
  agg_kernel<<<NROWS, 256, 0, stream>>>(vp, lw, aggT);
  trans_kernel<<<dim3(LQ / 64, BQ), 256, 0, stream>>>(aggT, out);
}

// Round 13
// 80.724 us; speedup vs baseline: 1.2575x; 1.2575x over previous
//
#include <hip/hip_runtime.h>
#include <hip/hip_bf16.h>

#define BQ 4
#define LQ 4096
#define DM 512
#define DK 64
#define NROWS (BQ * DK)        // 256
#define TOPK 16
#define CAND 32

typedef __attribute__((ext_vector_type(8))) short short8v;
typedef __attribute__((ext_vector_type(16))) float f32x16;

__device__ __forceinline__ unsigned short f2bf(float x) {
  unsigned u = __builtin_bit_cast(unsigned, x);
  return (unsigned short)((u + 0x7FFFu + ((u >> 16) & 1u)) >> 16);
}
__device__ __forceinline__ float bf2f(unsigned short h) {
  unsigned u = ((unsigned)h) << 16;
  return __builtin_bit_cast(float, u);
}

// MFMA->VALU drain (epilogue): nothing crosses; 32 wait cycles.
__device__ __forceinline__ void mfma_drain() {
  __builtin_amdgcn_sched_barrier(0);
  asm volatile("s_nop 7\n\ts_nop 7\n\ts_nop 7\n\ts_nop 7" ::: "memory");
  __builtin_amdgcn_sched_barrier(0);
}

// ---------------------------------------------------------------------------
// Kernel 0 v2: precompute W^T hi/lo bf16 in FRAGMENT-PACKED layout:
// wpack[((plane*2+nt)*32+ks)*512 + lane*8 + i] =
//   plane==0 ? hi : lo of Wq[16ks+8*(lane>>5)+i][nt*32+(lane&31)]
// grid 32 (one per ks), block 256 (lane x {plane,nt}).
// ---------------------------------------------------------------------------
__global__ __launch_bounds__(256) void wprep_kernel(
    const float* __restrict__ Wq, short* __restrict__ wpack) {
  const int ks = blockIdx.x;
  const int t = threadIdx.x;
  const int lane = t & 63, half = t >> 6;
  const int plane = half >> 1, nt = half & 1;
  const int r = nt * 32 + (lane & 31);
  const int kb = 16 * ks + 8 * (lane >> 5);
  short8v o;
#pragma unroll
  for (int i = 0; i < 8; ++i) {
    float v = Wq[(size_t)(kb + i) * DK + r];
    unsigned short h = f2bf(v);
    o[i] = plane ? (short)f2bf(v - bf2f(h)) : (short)h;
  }
  *(short8v*)(&wpack[(((size_t)plane * 2 + nt) * 32 + ks) * 512 + lane * 8]) = o;
}

// ---------------------------------------------------------------------------
// Kernel 1 v5: barrier-free split-bf16 MFMA projection.
// r12-proven hazard fencing (fused asm block, s_nop 4 lead / 7+3 trail).
// New: fragment-packed W (coalesced 16B/lane loads) + 1-step W prefetch.
// grid (128,1,3), block 256 = 4 independent waves; wave = 32 rows x 64 cols.
// ---------------------------------------------------------------------------
__global__ __launch_bounds__(256) void proj_kernel(
    const float* __restrict__ q_in, const float* __restrict__ k_in,
    const float* __restrict__ v_in, const short* __restrict__ wpack,
    const float* __restrict__ bq, float* __restrict__ ws) {
  const float* x = blockIdx.z == 0 ? q_in : (blockIdx.z == 1 ? k_in : v_in);
  float* outp = ws + (size_t)blockIdx.z * (size_t)(NROWS * LQ);

  __shared__ __align__(16) float ts[8 * 1088];   // epilogue scratch

  const int tid = threadIdx.x;
  const int l = tid & 63, wv = tid >> 6;
  const int gw = blockIdx.x * 4 + wv;            // 0..511
  const int R0 = gw * 32;
  const int koff = 8 * (l >> 5);

  const float* xb = x + (size_t)(R0 + (l & 31)) * DM + koff;
  const short* wp0 = wpack + l * 8;              // lane base

  f32x16 acc[2];
#pragma unroll
  for (int nt = 0; nt < 2; ++nt)
#pragma unroll
    for (int i = 0; i < 16; ++i) acc[nt][i] = 0.f;

  float4 a0[8], a1[8];
#pragma unroll
  for (int s = 0; s < 4; ++s) {
    a0[2 * s]     = *(const float4*)(xb + s * 16);
    a0[2 * s + 1] = *(const float4*)(xb + s * 16 + 4);
  }

  // W double-buffer: [0]=hi/nt0 [1]=lo/nt0 [2]=hi/nt1 [3]=lo/nt1
  short8v wc[4], wn[4];
#define WLOAD(dst, ksg)                                                      \
  do {                                                                       \
    dst[0] = *(const short8v*)(wp0 + (((ksg) + 0) << 9));                    \
    dst[1] = *(const short8v*)(wp0 + (((ksg) + 64) << 9));                   \
    dst[2] = *(const short8v*)(wp0 + (((ksg) + 32) << 9));                   \
    dst[3] = *(const short8v*)(wp0 + (((ksg) + 96) << 9));                   \
  } while (0)
  WLOAD(wc, 0);

#pragma unroll
  for (int kb = 0; kb < 8; ++kb) {
    if (kb < 7) {
#pragma unroll
      for (int s = 0; s < 4; ++s) {
        a1[2 * s]     = *(const float4*)(xb + (kb + 1) * 64 + s * 16);
        a1[2 * s + 1] = *(const float4*)(xb + (kb + 1) * 64 + s * 16 + 4);
      }
    }
#pragma unroll
    for (int s = 0; s < 4; ++s) {
      const int ksg = kb * 4 + s;
      if (ksg < 31) WLOAD(wn, ksg + 1);
      float f[8] = {a0[2 * s].x, a0[2 * s].y, a0[2 * s].z, a0[2 * s].w,
                    a0[2 * s + 1].x, a0[2 * s + 1].y, a0[2 * s + 1].z,
                    a0[2 * s + 1].w};
      short8v ah, al;
#pragma unroll
      for (int i = 0; i < 8; ++i) {
        unsigned short h = f2bf(f[i]);
        ah[i] = (short)h;
        al[i] = (short)f2bf(f[i] - bf2f(h));
      }
      asm volatile(
          "s_nop 4\n\t"
          "v_mfma_f32_32x32x16_bf16 %0, %2, %4, %0\n\t"
          "v_mfma_f32_32x32x16_bf16 %0, %2, %5, %0\n\t"
          "v_mfma_f32_32x32x16_bf16 %0, %3, %4, %0\n\t"
          "v_mfma_f32_32x32x16_bf16 %1, %2, %6, %1\n\t"
          "v_mfma_f32_32x32x16_bf16 %1, %2, %7, %1\n\t"
          "v_mfma_f32_32x32x16_bf16 %1, %3, %6, %1\n\t"
          "s_nop 7\n\t"
          "s_nop 3"
          : "+v"(acc[0]), "+v"(acc[1])
          : "v"(ah), "v"(al), "v"(wc[0]), "v"(wc[1]), "v"(wc[2]), "v"(wc[3]));
      if (ksg < 31) {
#pragma unroll
        for (int i = 0; i < 4; ++i) wc[i] = wn[i];
      }
    }
    if (kb < 7) {
#pragma unroll
      for (int i = 0; i < 8; ++i) a0[i] = a1[i];
    }
  }
#undef WLOAD

  // ---- epilogue: drain, bias + per-wave LDS transpose + stores ----
  mfma_drain();
  const int b = R0 >> 12, i0 = R0 & (LQ - 1);
  float bb[2] = {bq[l & 31], bq[32 + (l & 31)]};
#pragma unroll
  for (int nt = 0; nt < 2; ++nt) {
    float* area = ts + (wv * 2 + nt) * 1088;
#pragma unroll
    for (int r = 0; r < 16; ++r) {
      int io = (r & 3) + 8 * (r >> 2) + 4 * (l >> 5);
      area[(l & 31) * 34 + io] = acc[nt][r] + bb[nt];
    }
  }
  __syncthreads();
  const int e = l & 15, jg = l >> 4;
#pragma unroll
  for (int nt = 0; nt < 2; ++nt) {
    const float* area = ts + (wv * 2 + nt) * 1088;
#pragma unroll
    for (int p = 0; p < 8; ++p) {
      int jj = jg * 8 + p;
      float2 v = *reinterpret_cast<const float2*>(area + jj * 34 + e * 2);
      *reinterpret_cast<float2*>(
          &outp[((size_t)b * DK + nt * 32 + jj) * LQ + i0 + e * 2]) = v;
    }
  }
}

// ---------------------------------------------------------------------------
// Kernel 2 (r12-proven): fused corr+topk, 8 waves, scratch-free screen.
// ---------------------------------------------------------------------------
__global__ __launch_bounds__(512) void corr_topk_kernel(
    const float* __restrict__ qp, const float* __restrict__ kp,
    float* __restrict__ lw) {
  const int row = blockIdx.x;
  const int tid = threadIdx.x;
  __shared__ __align__(16) short qs[3 * 4112 + 4096];  // 32864 B; red overlay
  __shared__ __align__(16) short ks[4096];             // 8192 B
  __shared__ __align__(16) float qf[LQ];               // fp32 for refine
  __shared__ __align__(16) float kf[LQ];
  __shared__ unsigned wk[128];
  __shared__ unsigned scand[CAND];
  __shared__ float rS[CAND];
  __shared__ float ordv[TOPK]; __shared__ int ordl[TOPK];

  const float* qr = qp + ((size_t)row << 12);
  const float* kr = kp + ((size_t)row << 12);

  {
    const float4* q4 = (const float4*)qr;
    float4 v0 = q4[tid * 2], v1 = q4[tid * 2 + 1];
    float4 v2 = q4[(tid * 2 + 2) & 1023];
    ((float4*)qf)[tid * 2] = v0;
    ((float4*)qf)[tid * 2 + 1] = v1;
    float f[12] = {v0.x, v0.y, v0.z, v0.w, v1.x, v1.y, v1.z, v1.w,
                   v2.x, v2.y, v2.z, v2.w};
#pragma unroll
    for (int r = 0; r < 4; ++r) {
      short8v o;
#pragma unroll
      for (int i = 0; i < 8; ++i) o[i] = (short)f2bf(f[i + r]);
      *(short8v*)(&qs[r * 4112 + tid * 8]) = o;
    }
    const float4* k4 = (const float4*)kr;
    float4 w0 = k4[tid * 2], w1 = k4[tid * 2 + 1];
    ((float4*)kf)[tid * 2] = w0;
    ((float4*)kf)[tid * 2 + 1] = w1;
    float g[8] = {w0.x, w0.y, w0.z, w0.w, w1.x, w1.y, w1.z, w1.w};
    int Q = tid;
    int Qs = Q ^ ((Q >> 3) & 7);
    short8v o;
#pragma unroll
    for (int i = 0; i < 8; ++i) o[i] = (short)f2bf(g[i]);
    *(short8v*)(&ks[Qs << 3]) = o;
  }
  __syncthreads();

  const int l = tid & 63, wv = tid >> 6;    // 8 waves
  const int Oq = ((8 * (l >> 5) - 32 * (l & 31)) & 4095) >> 3;
  const int rB = (l & 31) & 3;
  const int Ce = (l & 31) + 8 * (l >> 5) - rB;
  const short* qb = qs + rB * 4112;

  f32x16 acc[4];
#pragma unroll
  for (int M = 0; M < 4; ++M)
#pragma unroll
    for (int i = 0; i < 16; ++i) acc[M][i] = 0.f;

  const int J0 = wv * 32;
#pragma unroll 2
  for (int jb = 0; jb < 32; ++jb) {
    const int J = J0 + jb;
    int e1 = (Ce + 16 * J) & 4095;
    int e2 = (e1 + 4) & 4095;
    uint2 blo = *(const uint2*)(qb + e1);
    uint2 bhi = *(const uint2*)(qb + e2);
    int4 bi; bi.x = blo.x; bi.y = blo.y; bi.z = bhi.x; bi.w = bhi.y;
    short8v bf = __builtin_bit_cast(short8v, bi);
    const int Dq = 2 * J;
#pragma unroll
    for (int M = 0; M < 4; ++M) {
      int Q = (Oq + Dq - 128 * M) & 511;
      Q ^= (Q >> 3) & 7;
      short8v af = *(const short8v*)(&ks[Q << 3]);
      asm volatile("s_nop 4\n\t"
                   "v_mfma_f32_32x32x16_bf16 %0, %1, %2, %0\n\t"
                   "s_nop 7\n\t"
                   "s_nop 3"
                   : "+v"(acc[M]) : "v"(af), "v"(bf));
    }
  }

  mfma_drain();
  __syncthreads();
  float* red = (float*)qs;               // 2 strips x 4096 f32
  const int strip = (wv & 1) * 4096;
  const int ch4 = (l >> 5) * 4, cn = l & 31;
#define RIDX(M, r) (strip + ((M) << 10) + 32 * (((r)&3) + 8 * ((r) >> 2) + ch4) + cn)
  if (wv < 2) {
#pragma unroll
    for (int M = 0; M < 4; ++M)
#pragma unroll
      for (int r = 0; r < 16; ++r) red[RIDX(M, r)] = acc[M][r];
  }
  __syncthreads();
  if (wv >= 2 && wv < 4) {
#pragma unroll
    for (int M = 0; M < 4; ++M)
#pragma unroll
      for (int r = 0; r < 16; ++r) red[RIDX(M, r)] += acc[M][r];
  }
  __syncthreads();
  if (wv >= 4 && wv < 6) {
#pragma unroll
    for (int M = 0; M < 4; ++M)
#pragma unroll
      for (int r = 0; r < 16; ++r) red[RIDX(M, r)] += acc[M][r];
  }
  __syncthreads();
  if (wv >= 6) {
#pragma unroll
    for (int M = 0; M < 4; ++M)
#pragma unroll
      for (int r = 0; r < 16; ++r) red[RIDX(M, r)] += acc[M][r];
  }
  __syncthreads();
#undef RIDX

  {
    unsigned key[8];
#pragma unroll
    for (int i = 0; i < 8; ++i) {
      int tau = wv * 512 + i * 64 + l;
      float v = red[tau] + red[4096 + tau];
      unsigned u = __builtin_bit_cast(unsigned, fabsf(v));
      key[i] = (u & 0xFFFFF000u) | (unsigned)(4095 - tau);
    }
    unsigned bkey = key[0];
#pragma unroll
    for (int i = 1; i < 8; ++i) bkey = key[i] > bkey ? key[i] : bkey;
    for (int round = 0; round < 16; ++round) {
      unsigned m = bkey;
#pragma unroll
      for (int off = 1; off < 64; off <<= 1) {
        unsigned o = __shfl_xor(m, off);
        m = o > m ? o : m;
      }
      if (l == 0) wk[wv * 16 + round] = m;
#pragma unroll
      for (int i = 0; i < 8; ++i) key[i] = (key[i] == m) ? 0u : key[i];
      bkey = key[0];
#pragma unroll
      for (int i = 1; i < 8; ++i) bkey = key[i] > bkey ? key[i] : bkey;
    }
  }
  __syncthreads();

  if (tid < 128) {
    unsigned ki = wk[tid];
    int rank = 0;
    for (int j = 0; j < 128; ++j) rank += (wk[j] > ki);
    if (rank < CAND) scand[rank] = ki;
  }
  __syncthreads();

  {
    const int ci = tid >> 4, sub = tid & 15;
    const int lag = 4095 - (int)(scand[ci] & 0xFFFu);
    float S0 = 0.f, S1 = 0.f, S2 = 0.f, S3 = 0.f;
    for (int it = 0; it < 256; it += 4) {
      int t0 = (it + 0) * 16 + sub, t1 = (it + 1) * 16 + sub;
      int t2 = (it + 2) * 16 + sub, t3 = (it + 3) * 16 + sub;
      S0 = fmaf(kf[t0], qf[(t0 + lag) & 4095], S0);
      S1 = fmaf(kf[t1], qf[(t1 + lag) & 4095], S1);
      S2 = fmaf(kf[t2], qf[(t2 + lag) & 4095], S2);
      S3 = fmaf(kf[t3], qf[(t3 + lag) & 4095], S3);
    }
    float S = (S0 + S1) + (S2 + S3);
    S += __shfl_xor(S, 1);
    S += __shfl_xor(S, 2);
    S += __shfl_xor(S, 4);
    S += __shfl_xor(S, 8);
    if (sub == 0) rS[ci] = S;
  }
  __syncthreads();

  if (tid < CAND) {
    float vi = fabsf(rS[tid]);
    int ii = 4095 - (int)(scand[tid] & 0xFFFu);
    int rank = 0;
    for (int j = 0; j < CAND; ++j) {
      float vj = fabsf(rS[j]);
      int ij = 4095 - (int)(scand[j] & 0xFFFu);
      rank += (vj > vi) || (vj == vi && ij < ii);
    }
    if (rank < TOPK) { ordv[rank] = vi; ordl[rank] = ii; }
  }
  __syncthreads();

  if (tid == 0) {
    float m0 = ordv[0], s = 0.f, e[TOPK];
    for (int k = 0; k < TOPK; ++k) { e[k] = expf(ordv[k] - m0); s += e[k]; }
    float inv = 1.f / s;
    int* ip = (int*)(lw + (size_t)row * 32);
    for (int k = 0; k < TOPK; ++k) {
      ip[k] = ordl[k];
      ((float*)ip)[TOPK + k] = e[k] * inv;
    }
  }
}

// ---------------------------------------------------------------------------
// Kernel 4: aggregation  aggT[row][t] = sum_k w_k * v[row][(t+lag_k)%L]
// ---------------------------------------------------------------------------
__global__ void agg_kernel(const float* __restrict__ vpT,
                           const float* __restrict__ lw,
                           float* __restrict__ aggT) {
  const int row = blockIdx.x, tid = threadIdx.x;
  __shared__ __align__(16) float vr[2 * LQ];
  __shared__ float w[TOPK]; __shared__ int lg[TOPK];

  const float* v0 = vpT + (size_t)row * LQ;
  for (int x = tid; x < LQ; x += 256) {
    float val = v0[x];
    vr[x] = val; vr[x + LQ] = val;
  }
  if (tid < TOPK) {
    lg[tid] = ((const int*)(lw + (size_t)row * 32))[tid];
    w[tid] = lw[(size_t)row * 32 + TOPK + tid];
  }
  __syncthreads();

  float wr[TOPK]; int lr[TOPK];
#pragma unroll
  for (int k = 0; k < TOPK; ++k) { wr[k] = w[k]; lr[k] = lg[k]; }

  for (int m = 0; m < 16; ++m) {
    int t = m * 256 + tid;
    float a = 0.f;
#pragma unroll
    for (int k = 0; k < TOPK; ++k) a = fmaf(wr[k], vr[t + lr[k]], a);
    aggT[(size_t)row * LQ + t] = a;
  }
}

// ---------------------------------------------------------------------------
// Kernel 5: transpose + head-broadcast  out[b][t][c] = aggT[b][c&63][t]
// ---------------------------------------------------------------------------
__global__ void trans_kernel(const float* __restrict__ aggT,
                             float* __restrict__ out) {
  const int b = blockIdx.y;
  const int t0 = blockIdx.x * 64;
  const int tid = threadIdx.x;
  __shared__ float ts[64][65];

#pragma unroll
  for (int v = 0; v < 16; ++v) {
    int f = v * 256 + tid;
    int d = f >> 6, tt = f & 63;
    ts[d][tt] = aggT[((size_t)b * DK + d) * LQ + t0 + tt];
  }
  __syncthreads();

#pragma unroll
  for (int v = 0; v < 128; ++v) {
    int f = v * 256 + tid;
    int tt = f >> 9, c = f & 511;
    out[((size_t)b * LQ + t0 + tt) * (8 * DK) + c] = ts[c & 63][tt];
  }
}

// ---------------------------------------------------------------------------
// ws layout (floats): [0,1M) qp  [1M,2M) kp  [2M,3M) vp
//   [3M,+8K) lw  [4M,5M) aggT  [5M,+32K floats) wpack (128KB)
// ---------------------------------------------------------------------------
extern "C" void kernel_launch(void* const* d_in, const int* in_sizes, int n_in,
                              void* d_out, int out_size, void* d_ws, size_t ws_size,
                              hipStream_t stream) {
  const float* q_in = (const float*)d_in[0];
  const float* k_in = (const float*)d_in[1];
  const float* v_in = (const float*)d_in[2];
  const float* Wq   = (const float*)d_in[3];
  const float* bq   = (const float*)d_in[4];
  float* out = (float*)d_out;
  float* ws  = (float*)d_ws;

  const size_t M = (size_t)NROWS * LQ;        // 1,048,576 floats
  float* qp    = ws;
  float* kp    = ws + M;
  float* vp    = ws + 2 * M;
  float* lw    = ws + 3 * M;
  float* aggT  = ws + 4 * M;
  short* wpack = (short*)(ws + 5 * M);

  wprep_kernel<<<32, 256, 0, stream>>>(Wq, wpack);
  proj_kernel<<<dim3(128, 1, 3), 256, 0, stream>>>(q_in, k_in, v_in, wpack,
                                                   bq, ws);
  corr_topk_kernel<<<NROWS, 512, 0, stream>>>(qp, kp, lw);
  agg_kernel<<<NROWS, 256, 0, stream>>>(vp, lw, aggT);
  trans_kernel<<<dim3(LQ / 64, BQ), 256, 0, stream>>>(aggT, out);
}

// Round 14
// 76.149 us; speedup vs baseline: 1.3331x; 1.0601x over previous
//
#include <hip/hip_runtime.h>
#include <hip/hip_bf16.h>

#define BQ 4
#define LQ 4096
#define DM 512
#define DK 64
#define NROWS (BQ * DK)        // 256
#define TOPK 16
#define CAND 32

typedef __attribute__((ext_vector_type(8))) short short8v;
typedef __attribute__((ext_vector_type(16))) float f32x16;

__device__ __forceinline__ unsigned short f2bf(float x) {
  unsigned u = __builtin_bit_cast(unsigned, x);
  return (unsigned short)((u + 0x7FFFu + ((u >> 16) & 1u)) >> 16);
}
__device__ __forceinline__ float bf2f(unsigned short h) {
  unsigned u = ((unsigned)h) << 16;
  return __builtin_bit_cast(float, u);
}

// MFMA->VALU drain (epilogue): nothing crosses; 32 wait cycles.
__device__ __forceinline__ void mfma_drain() {
  __builtin_amdgcn_sched_barrier(0);
  asm volatile("s_nop 7\n\ts_nop 7\n\ts_nop 7\n\ts_nop 7" ::: "memory");
  __builtin_amdgcn_sched_barrier(0);
}

// ---------------------------------------------------------------------------
// Kernel 0 (r13-proven): W^T hi/lo bf16 in fragment-packed layout.
// wpack[((plane*2+nt)*32+ks)*512 + lane*8 + i]
// ---------------------------------------------------------------------------
__global__ __launch_bounds__(256) void wprep_kernel(
    const float* __restrict__ Wq, short* __restrict__ wpack) {
  const int ks = blockIdx.x;
  const int t = threadIdx.x;
  const int lane = t & 63, half = t >> 6;
  const int plane = half >> 1, nt = half & 1;
  const int r = nt * 32 + (lane & 31);
  const int kb = 16 * ks + 8 * (lane >> 5);
  short8v o;
#pragma unroll
  for (int i = 0; i < 8; ++i) {
    float v = Wq[(size_t)(kb + i) * DK + r];
    unsigned short h = f2bf(v);
    o[i] = plane ? (short)f2bf(v - bf2f(h)) : (short)h;
  }
  *(short8v*)(&wpack[(((size_t)plane * 2 + nt) * 32 + ks) * 512 + lane * 8]) = o;
}

// ---------------------------------------------------------------------------
// Kernel 1 v6: K-SPLIT barrier-free split-bf16 MFMA projection.
// grid (256,1,3), block 256 = 4 waves: wave = (tile in {0,1}) x (kh in {0,1}).
// Each wave: 32 rows x 64 cols over K-half [kh*256, +256) -> 2x waves/CU vs
// r13 (MLP-bound fix). Partials merged via LDS; kh=0 waves run the epilogue.
// r12-proven hazard fencing (fused asm, s_nop 4 lead / 7+3 trail) unchanged.
// ---------------------------------------------------------------------------
__global__ __launch_bounds__(256) void proj_kernel(
    const float* __restrict__ q_in, const float* __restrict__ k_in,
    const float* __restrict__ v_in, const short* __restrict__ wpack,
    const float* __restrict__ bq, float* __restrict__ ws) {
  const float* x = blockIdx.z == 0 ? q_in : (blockIdx.z == 1 ? k_in : v_in);
  float* outp = ws + (size_t)blockIdx.z * (size_t)(NROWS * LQ);

  __shared__ __align__(16) float smem[4352];   // red[4096] / ts[4352] overlay

  const int tid = threadIdx.x;
  const int l = tid & 63, wv = tid >> 6;
  const int tile = wv >> 1, kh = wv & 1;
  const int R0 = blockIdx.x * 64 + tile * 32;
  const int koff = 8 * (l >> 5);

  const float* xb = x + (size_t)(R0 + (l & 31)) * DM + kh * 256 + koff;
  const short* wp0 = wpack + l * 8;            // lane base

  f32x16 acc[2];
#pragma unroll
  for (int nt = 0; nt < 2; ++nt)
#pragma unroll
    for (int i = 0; i < 16; ++i) acc[nt][i] = 0.f;

  float4 a0[8], a1[8];
#pragma unroll
  for (int s = 0; s < 4; ++s) {
    a0[2 * s]     = *(const float4*)(xb + s * 16);
    a0[2 * s + 1] = *(const float4*)(xb + s * 16 + 4);
  }

  // W double-buffer: [0]=hi/nt0 [1]=lo/nt0 [2]=hi/nt1 [3]=lo/nt1
  short8v wc[4], wn[4];
#define WLOAD(dst, ksl)                                                      \
  do {                                                                       \
    const int kg = kh * 16 + (ksl);                                          \
    dst[0] = *(const short8v*)(wp0 + ((kg + 0) << 9));                       \
    dst[1] = *(const short8v*)(wp0 + ((kg + 64) << 9));                      \
    dst[2] = *(const short8v*)(wp0 + ((kg + 32) << 9));                      \
    dst[3] = *(const short8v*)(wp0 + ((kg + 96) << 9));                      \
  } while (0)
  WLOAD(wc, 0);

#pragma unroll
  for (int kb = 0; kb < 4; ++kb) {
    if (kb < 3) {
#pragma unroll
      for (int s = 0; s < 4; ++s) {
        a1[2 * s]     = *(const float4*)(xb + (kb + 1) * 64 + s * 16);
        a1[2 * s + 1] = *(const float4*)(xb + (kb + 1) * 64 + s * 16 + 4);
      }
    }
#pragma unroll
    for (int s = 0; s < 4; ++s) {
      const int ksl = kb * 4 + s;
      if (ksl < 15) WLOAD(wn, ksl + 1);
      float f[8] = {a0[2 * s].x, a0[2 * s].y, a0[2 * s].z, a0[2 * s].w,
                    a0[2 * s + 1].x, a0[2 * s + 1].y, a0[2 * s + 1].z,
                    a0[2 * s + 1].w};
      short8v ah, al;
#pragma unroll
      for (int i = 0; i < 8; ++i) {
        unsigned short h = f2bf(f[i]);
        ah[i] = (short)h;
        al[i] = (short)f2bf(f[i] - bf2f(h));
      }
      asm volatile(
          "s_nop 4\n\t"
          "v_mfma_f32_32x32x16_bf16 %0, %2, %4, %0\n\t"
          "v_mfma_f32_32x32x16_bf16 %0, %2, %5, %0\n\t"
          "v_mfma_f32_32x32x16_bf16 %0, %3, %4, %0\n\t"
          "v_mfma_f32_32x32x16_bf16 %1, %2, %6, %1\n\t"
          "v_mfma_f32_32x32x16_bf16 %1, %2, %7, %1\n\t"
          "v_mfma_f32_32x32x16_bf16 %1, %3, %6, %1\n\t"
          "s_nop 7\n\t"
          "s_nop 3"
          : "+v"(acc[0]), "+v"(acc[1])
          : "v"(ah), "v"(al), "v"(wc[0]), "v"(wc[1]), "v"(wc[2]), "v"(wc[3]));
      if (ksl < 15) {
#pragma unroll
        for (int i = 0; i < 4; ++i) wc[i] = wn[i];
      }
    }
    if (kb < 3) {
#pragma unroll
      for (int i = 0; i < 8; ++i) a0[i] = a1[i];
    }
  }
#undef WLOAD

  // ---- merge K-halves via LDS (kh=1 writes, kh=0 adds) ----
  mfma_drain();
  if (kh == 1) {
#pragma unroll
    for (int nt = 0; nt < 2; ++nt)
#pragma unroll
      for (int r = 0; r < 16; ++r)
        smem[tile * 2048 + nt * 1024 + r * 64 + l] = acc[nt][r];
  }
  __syncthreads();
  if (kh == 0) {
#pragma unroll
    for (int nt = 0; nt < 2; ++nt)
#pragma unroll
      for (int r = 0; r < 16; ++r)
        acc[nt][r] += smem[tile * 2048 + nt * 1024 + r * 64 + l];
  }
  __syncthreads();   // red region dead; ts overlay safe

  // ---- epilogue (kh=0 waves): bias + per-wave LDS transpose + stores ----
  if (kh == 0) {
    const int b = R0 >> 12, i0 = R0 & (LQ - 1);
    float bb[2] = {bq[l & 31], bq[32 + (l & 31)]};
#pragma unroll
    for (int nt = 0; nt < 2; ++nt) {
      float* area = smem + (tile * 2 + nt) * 1088;
#pragma unroll
      for (int r = 0; r < 16; ++r) {
        int io = (r & 3) + 8 * (r >> 2) + 4 * (l >> 5);
        area[(l & 31) * 34 + io] = acc[nt][r] + bb[nt];
      }
      const int e = l & 15, jg = l >> 4;
#pragma unroll
      for (int p = 0; p < 8; ++p) {
        int jj = jg * 8 + p;
        float2 v = *reinterpret_cast<const float2*>(area + jj * 34 + e * 2);
        *reinterpret_cast<float2*>(
            &outp[((size_t)b * DK + nt * 32 + jj) * LQ + i0 + e * 2]) = v;
      }
    }
  }
}

// ---------------------------------------------------------------------------
// Kernel 2 (r12-proven): fused corr+topk, 8 waves, scratch-free screen.
// ---------------------------------------------------------------------------
__global__ __launch_bounds__(512) void corr_topk_kernel(
    const float* __restrict__ qp, const float* __restrict__ kp,
    float* __restrict__ lw) {
  const int row = blockIdx.x;
  const int tid = threadIdx.x;
  __shared__ __align__(16) short qs[3 * 4112 + 4096];  // 32864 B; red overlay
  __shared__ __align__(16) short ks[4096];             // 8192 B
  __shared__ __align__(16) float qf[LQ];               // fp32 for refine
  __shared__ __align__(16) float kf[LQ];
  __shared__ unsigned wk[128];
  __shared__ unsigned scand[CAND];
  __shared__ float rS[CAND];
  __shared__ float ordv[TOPK]; __shared__ int ordl[TOPK];

  const float* qr = qp + ((size_t)row << 12);
  const float* kr = kp + ((size_t)row << 12);

  {
    const float4* q4 = (const float4*)qr;
    float4 v0 = q4[tid * 2], v1 = q4[tid * 2 + 1];
    float4 v2 = q4[(tid * 2 + 2) & 1023];
    ((float4*)qf)[tid * 2] = v0;
    ((float4*)qf)[tid * 2 + 1] = v1;
    float f[12] = {v0.x, v0.y, v0.z, v0.w, v1.x, v1.y, v1.z, v1.w,
                   v2.x, v2.y, v2.z, v2.w};
#pragma unroll
    for (int r = 0; r < 4; ++r) {
      short8v o;
#pragma unroll
      for (int i = 0; i < 8; ++i) o[i] = (short)f2bf(f[i + r]);
      *(short8v*)(&qs[r * 4112 + tid * 8]) = o;
    }
    const float4* k4 = (const float4*)kr;
    float4 w0 = k4[tid * 2], w1 = k4[tid * 2 + 1];
    ((float4*)kf)[tid * 2] = w0;
    ((float4*)kf)[tid * 2 + 1] = w1;
    float g[8] = {w0.x, w0.y, w0.z, w0.w, w1.x, w1.y, w1.z, w1.w};
    int Q = tid;
    int Qs = Q ^ ((Q >> 3) & 7);
    short8v o;
#pragma unroll
    for (int i = 0; i < 8; ++i) o[i] = (short)f2bf(g[i]);
    *(short8v*)(&ks[Qs << 3]) = o;
  }
  __syncthreads();

  const int l = tid & 63, wv = tid >> 6;    // 8 waves
  const int Oq = ((8 * (l >> 5) - 32 * (l & 31)) & 4095) >> 3;
  const int rB = (l & 31) & 3;
  const int Ce = (l & 31) + 8 * (l >> 5) - rB;
  const short* qb = qs + rB * 4112;

  f32x16 acc[4];
#pragma unroll
  for (int M = 0; M < 4; ++M)
#pragma unroll
    for (int i = 0; i < 16; ++i) acc[M][i] = 0.f;

  const int J0 = wv * 32;
#pragma unroll 2
  for (int jb = 0; jb < 32; ++jb) {
    const int J = J0 + jb;
    int e1 = (Ce + 16 * J) & 4095;
    int e2 = (e1 + 4) & 4095;
    uint2 blo = *(const uint2*)(qb + e1);
    uint2 bhi = *(const uint2*)(qb + e2);
    int4 bi; bi.x = blo.x; bi.y = blo.y; bi.z = bhi.x; bi.w = bhi.y;
    short8v bf = __builtin_bit_cast(short8v, bi);
    const int Dq = 2 * J;
#pragma unroll
    for (int M = 0; M < 4; ++M) {
      int Q = (Oq + Dq - 128 * M) & 511;
      Q ^= (Q >> 3) & 7;
      short8v af = *(const short8v*)(&ks[Q << 3]);
      asm volatile("s_nop 4\n\t"
                   "v_mfma_f32_32x32x16_bf16 %0, %1, %2, %0\n\t"
                   "s_nop 7\n\t"
                   "s_nop 3"
                   : "+v"(acc[M]) : "v"(af), "v"(bf));
    }
  }

  mfma_drain();
  __syncthreads();
  float* red = (float*)qs;               // 2 strips x 4096 f32
  const int strip = (wv & 1) * 4096;
  const int ch4 = (l >> 5) * 4, cn = l & 31;
#define RIDX(M, r) (strip + ((M) << 10) + 32 * (((r)&3) + 8 * ((r) >> 2) + ch4) + cn)
  if (wv < 2) {
#pragma unroll
    for (int M = 0; M < 4; ++M)
#pragma unroll
      for (int r = 0; r < 16; ++r) red[RIDX(M, r)] = acc[M][r];
  }
  __syncthreads();
  if (wv >= 2 && wv < 4) {
#pragma unroll
    for (int M = 0; M < 4; ++M)
#pragma unroll
      for (int r = 0; r < 16; ++r) red[RIDX(M, r)] += acc[M][r];
  }
  __syncthreads();
  if (wv >= 4 && wv < 6) {
#pragma unroll
    for (int M = 0; M < 4; ++M)
#pragma unroll
      for (int r = 0; r < 16; ++r) red[RIDX(M, r)] += acc[M][r];
  }
  __syncthreads();
  if (wv >= 6) {
#pragma unroll
    for (int M = 0; M < 4; ++M)
#pragma unroll
      for (int r = 0; r < 16; ++r) red[RIDX(M, r)] += acc[M][r];
  }
  __syncthreads();
#undef RIDX

  {
    unsigned key[8];
#pragma unroll
    for (int i = 0; i < 8; ++i) {
      int tau = wv * 512 + i * 64 + l;
      float v = red[tau] + red[4096 + tau];
      unsigned u = __builtin_bit_cast(unsigned, fabsf(v));
      key[i] = (u & 0xFFFFF000u) | (unsigned)(4095 - tau);
    }
    unsigned bkey = key[0];
#pragma unroll
    for (int i = 1; i < 8; ++i) bkey = key[i] > bkey ? key[i] : bkey;
    for (int round = 0; round < 16; ++round) {
      unsigned m = bkey;
#pragma unroll
      for (int off = 1; off < 64; off <<= 1) {
        unsigned o = __shfl_xor(m, off);
        m = o > m ? o : m;
      }
      if (l == 0) wk[wv * 16 + round] = m;
#pragma unroll
      for (int i = 0; i < 8; ++i) key[i] = (key[i] == m) ? 0u : key[i];
      bkey = key[0];
#pragma unroll
      for (int i = 1; i < 8; ++i) bkey = key[i] > bkey ? key[i] : bkey;
    }
  }
  __syncthreads();

  if (tid < 128) {
    unsigned ki = wk[tid];
    int rank = 0;
    for (int j = 0; j < 128; ++j) rank += (wk[j] > ki);
    if (rank < CAND) scand[rank] = ki;
  }
  __syncthreads();

  {
    const int ci = tid >> 4, sub = tid & 15;
    const int lag = 4095 - (int)(scand[ci] & 0xFFFu);
    float S0 = 0.f, S1 = 0.f, S2 = 0.f, S3 = 0.f;
    for (int it = 0; it < 256; it += 4) {
      int t0 = (it + 0) * 16 + sub, t1 = (it + 1) * 16 + sub;
      int t2 = (it + 2) * 16 + sub, t3 = (it + 3) * 16 + sub;
      S0 = fmaf(kf[t0], qf[(t0 + lag) & 4095], S0);
      S1 = fmaf(kf[t1], qf[(t1 + lag) & 4095], S1);
      S2 = fmaf(kf[t2], qf[(t2 + lag) & 4095], S2);
      S3 = fmaf(kf[t3], qf[(t3 + lag) & 4095], S3);
    }
    float S = (S0 + S1) + (S2 + S3);
    S += __shfl_xor(S, 1);
    S += __shfl_xor(S, 2);
    S += __shfl_xor(S, 4);
    S += __shfl_xor(S, 8);
    if (sub == 0) rS[ci] = S;
  }
  __syncthreads();

  if (tid < CAND) {
    float vi = fabsf(rS[tid]);
    int ii = 4095 - (int)(scand[tid] & 0xFFFu);
    int rank = 0;
    for (int j = 0; j < CAND; ++j) {
      float vj = fabsf(rS[j]);
      int ij = 4095 - (int)(scand[j] & 0xFFFu);
      rank += (vj > vi) || (vj == vi && ij < ii);
    }
    if (rank < TOPK) { ordv[rank] = vi; ordl[rank] = ii; }
  }
  __syncthreads();

  if (tid == 0) {
    float m0 = ordv[0], s = 0.f, e[TOPK];
    for (int k = 0; k < TOPK; ++k) { e[k] = expf(ordv[k] - m0); s += e[k]; }
    float inv = 1.f / s;
    int* ip = (int*)(lw + (size_t)row * 32);
    for (int k = 0; k < TOPK; ++k) {
      ip[k] = ordl[k];
      ((float*)ip)[TOPK + k] = e[k] * inv;
    }
  }
}

// ---------------------------------------------------------------------------
// Kernel 4: aggregation  aggT[row][t] = sum_k w_k * v[row][(t+lag_k)%L]
// ---------------------------------------------------------------------------
__global__ void agg_kernel(const float* __restrict__ vpT,
                           const float* __restrict__ lw,
                           float* __restrict__ aggT) {
  const int row = blockIdx.x, tid = threadIdx.x;
  __shared__ __align__(16) float vr[2 * LQ];
  __shared__ float w[TOPK]; __shared__ int lg[TOPK];

  const float* v0 = vpT + (size_t)row * LQ;
  for (int x = tid; x < LQ; x += 256) {
    float val = v0[x];
    vr[x] = val; vr[x + LQ] = val;
  }
  if (tid < TOPK) {
    lg[tid] = ((const int*)(lw + (size_t)row * 32))[tid];
    w[tid] = lw[(size_t)row * 32 + TOPK + tid];
  }
  __syncthreads();

  float wr[TOPK]; int lr[TOPK];
#pragma unroll
  for (int k = 0; k < TOPK; ++k) { wr[k] = w[k]; lr[k] = lg[k]; }

  for (int m = 0; m < 16; ++m) {
    int t = m * 256 + tid;
    float a = 0.f;
#pragma unroll
    for (int k = 0; k < TOPK; ++k) a = fmaf(wr[k], vr[t + lr[k]], a);
    aggT[(size_t)row * LQ + t] = a;
  }
}

// ---------------------------------------------------------------------------
// Kernel 5: transpose + head-broadcast  out[b][t][c] = aggT[b][c&63][t]
// ---------------------------------------------------------------------------
__global__ void trans_kernel(const float* __restrict__ aggT,
                             float* __restrict__ out) {
  const int b = blockIdx.y;
  const int t0 = blockIdx.x * 64;
  const int tid = threadIdx.x;
  __shared__ float ts[64][65];

#pragma unroll
  for (int v = 0; v < 16; ++v) {
    int f = v * 256 + tid;
    int d = f >> 6, tt = f & 63;
    ts[d][tt] = aggT[((size_t)b * DK + d) * LQ + t0 + tt];
  }
  __syncthreads();

#pragma unroll
  for (int v = 0; v < 128; ++v) {
    int f = v * 256 + tid;
    int tt = f >> 9, c = f & 511;
    out[((size_t)b * LQ + t0 + tt) * (8 * DK) + c] = ts[c & 63][tt];
  }
}

// ---------------------------------------------------------------------------
// ws layout (floats): [0,1M) qp  [1M,2M) kp  [2M,3M) vp
//   [3M,+8K) lw  [4M,5M) aggT  [5M,+32K floats) wpack (128KB)
// ---------------------------------------------------------------------------
extern "C" void kernel_launch(void* const* d_in, const int* in_sizes, int n_in,
                              void* d_out, int out_size, void* d_ws, size_t ws_size,
                              hipStream_t stream) {
  const float* q_in = (const float*)d_in[0];
  const float* k_in = (const float*)d_in[1];
  const float* v_in = (const float*)d_in[2];
  const float* Wq   = (const float*)d_in[3];
  const float* bq   = (const float*)d_in[4];
  float* out = (float*)d_out;
  float* ws  = (float*)d_ws;

  const size_t M = (size_t)NROWS * LQ;        // 1,048,576 floats
  float* qp    = ws;
  float* kp    = ws + M;
  float* vp    = ws + 2 * M;
  float* lw    = ws + 3 * M;
  float* aggT  = ws + 4 * M;
  short* wpack = (short*)(ws + 5 * M);

  wprep_kernel<<<32, 256, 0, stream>>>(Wq, wpack);
  proj_kernel<<<dim3(256, 1, 3), 256, 0, stream>>>(q_in, k_in, v_in, wpack,
                                                   bq, ws);
  corr_topk_kernel<<<NROWS, 512, 0, stream>>>(qp, kp, lw);
  agg_kernel<<<NROWS, 256, 0, stream>>>(vp, lw, aggT);
  trans_kernel<<<dim3(LQ / 64, BQ), 256, 0, stream>>>(aggT, out);
}

// Round 15
// 75.305 us; speedup vs baseline: 1.3480x; 1.0112x over previous
//
#include <hip/hip_runtime.h>
#include <hip/hip_bf16.h>

#define BQ 4
#define LQ 4096
#define DM 512
#define DK 64
#define NROWS (BQ * DK)        // 256
#define TOPK 16
#define CAND 32

typedef __attribute__((ext_vector_type(8))) short short8v;
typedef __attribute__((ext_vector_type(16))) float f32x16;

__device__ __forceinline__ unsigned short f2bf(float x) {
  unsigned u = __builtin_bit_cast(unsigned, x);
  return (unsigned short)((u + 0x7FFFu + ((u >> 16) & 1u)) >> 16);
}
__device__ __forceinline__ float bf2f(unsigned short h) {
  unsigned u = ((unsigned)h) << 16;
  return __builtin_bit_cast(float, u);
}

// MFMA->VALU drain (epilogue): nothing crosses; 32 wait cycles.
__device__ __forceinline__ void mfma_drain() {
  __builtin_amdgcn_sched_barrier(0);
  asm volatile("s_nop 7\n\ts_nop 7\n\ts_nop 7\n\ts_nop 7" ::: "memory");
  __builtin_amdgcn_sched_barrier(0);
}

// ---------------------------------------------------------------------------
// Kernel 0 (r13-proven): W^T hi/lo bf16 in fragment-packed layout.
// wpack[((plane*2+nt)*32+ks)*512 + lane*8 + i]
// ---------------------------------------------------------------------------
__global__ __launch_bounds__(256) void wprep_kernel(
    const float* __restrict__ Wq, short* __restrict__ wpack) {
  const int ks = blockIdx.x;
  const int t = threadIdx.x;
  const int lane = t & 63, half = t >> 6;
  const int plane = half >> 1, nt = half & 1;
  const int r = nt * 32 + (lane & 31);
  const int kb = 16 * ks + 8 * (lane >> 5);
  short8v o;
#pragma unroll
  for (int i = 0; i < 8; ++i) {
    float v = Wq[(size_t)(kb + i) * DK + r];
    unsigned short h = f2bf(v);
    o[i] = plane ? (short)f2bf(v - bf2f(h)) : (short)h;
  }
  *(short8v*)(&wpack[(((size_t)plane * 2 + nt) * 32 + ks) * 512 + lane * 8]) = o;
}

// ---------------------------------------------------------------------------
// Kernel 1 v7: K-split barrier-free split-bf16 MFMA projection.
// __launch_bounds__(256,3): VGPR cap ~170 so the a1/wn software prefetches
// stay materialized (r14's 80-VGPR allocation sank them -> serial latency).
// grid (256,1,3), block 256 = 4 waves: (tile in {0,1}) x (kh in {0,1}).
// r12-proven hazard fencing (fused asm, s_nop 4 lead / 7+3 trail) unchanged.
// ---------------------------------------------------------------------------
__global__ __launch_bounds__(256, 3) void proj_kernel(
    const float* __restrict__ q_in, const float* __restrict__ k_in,
    const float* __restrict__ v_in, const short* __restrict__ wpack,
    const float* __restrict__ bq, float* __restrict__ ws) {
  const float* x = blockIdx.z == 0 ? q_in : (blockIdx.z == 1 ? k_in : v_in);
  float* outp = ws + (size_t)blockIdx.z * (size_t)(NROWS * LQ);

  __shared__ __align__(16) float smem[4352];   // red[4096] / ts[4352] overlay

  const int tid = threadIdx.x;
  const int l = tid & 63, wv = tid >> 6;
  const int tile = wv >> 1, kh = wv & 1;
  const int R0 = blockIdx.x * 64 + tile * 32;
  const int koff = 8 * (l >> 5);

  const float* xb = x + (size_t)(R0 + (l & 31)) * DM + kh * 256 + koff;
  const short* wp0 = wpack + l * 8;            // lane base

  f32x16 acc[2];
#pragma unroll
  for (int nt = 0; nt < 2; ++nt)
#pragma unroll
    for (int i = 0; i < 16; ++i) acc[nt][i] = 0.f;

  float4 a0[8], a1[8];
#pragma unroll
  for (int s = 0; s < 4; ++s) {
    a0[2 * s]     = *(const float4*)(xb + s * 16);
    a0[2 * s + 1] = *(const float4*)(xb + s * 16 + 4);
  }

  // W double-buffer: [0]=hi/nt0 [1]=lo/nt0 [2]=hi/nt1 [3]=lo/nt1
  short8v wc[4], wn[4];
#define WLOAD(dst, ksl)                                                      \
  do {                                                                       \
    const int kg = kh * 16 + (ksl);                                          \
    dst[0] = *(const short8v*)(wp0 + ((kg + 0) << 9));                       \
    dst[1] = *(const short8v*)(wp0 + ((kg + 64) << 9));                      \
    dst[2] = *(const short8v*)(wp0 + ((kg + 32) << 9));                      \
    dst[3] = *(const short8v*)(wp0 + ((kg + 96) << 9));                      \
  } while (0)
  WLOAD(wc, 0);

#pragma unroll
  for (int kb = 0; kb < 4; ++kb) {
    if (kb < 3) {
#pragma unroll
      for (int s = 0; s < 4; ++s) {
        a1[2 * s]     = *(const float4*)(xb + (kb + 1) * 64 + s * 16);
        a1[2 * s + 1] = *(const float4*)(xb + (kb + 1) * 64 + s * 16 + 4);
      }
    }
#pragma unroll
    for (int s = 0; s < 4; ++s) {
      const int ksl = kb * 4 + s;
      if (ksl < 15) WLOAD(wn, ksl + 1);
      float f[8] = {a0[2 * s].x, a0[2 * s].y, a0[2 * s].z, a0[2 * s].w,
                    a0[2 * s + 1].x, a0[2 * s + 1].y, a0[2 * s + 1].z,
                    a0[2 * s + 1].w};
      short8v ah, al;
#pragma unroll
      for (int i = 0; i < 8; ++i) {
        unsigned short h = f2bf(f[i]);
        ah[i] = (short)h;
        al[i] = (short)f2bf(f[i] - bf2f(h));
      }
      asm volatile(
          "s_nop 4\n\t"
          "v_mfma_f32_32x32x16_bf16 %0, %2, %4, %0\n\t"
          "v_mfma_f32_32x32x16_bf16 %0, %2, %5, %0\n\t"
          "v_mfma_f32_32x32x16_bf16 %0, %3, %4, %0\n\t"
          "v_mfma_f32_32x32x16_bf16 %1, %2, %6, %1\n\t"
          "v_mfma_f32_32x32x16_bf16 %1, %2, %7, %1\n\t"
          "v_mfma_f32_32x32x16_bf16 %1, %3, %6, %1\n\t"
          "s_nop 7\n\t"
          "s_nop 3"
          : "+v"(acc[0]), "+v"(acc[1])
          : "v"(ah), "v"(al), "v"(wc[0]), "v"(wc[1]), "v"(wc[2]), "v"(wc[3]));
      if (ksl < 15) {
#pragma unroll
        for (int i = 0; i < 4; ++i) wc[i] = wn[i];
      }
    }
    if (kb < 3) {
#pragma unroll
      for (int i = 0; i < 8; ++i) a0[i] = a1[i];
    }
  }
#undef WLOAD

  // ---- merge K-halves via LDS (kh=1 writes, kh=0 adds) ----
  mfma_drain();
  if (kh == 1) {
#pragma unroll
    for (int nt = 0; nt < 2; ++nt)
#pragma unroll
      for (int r = 0; r < 16; ++r)
        smem[tile * 2048 + nt * 1024 + r * 64 + l] = acc[nt][r];
  }
  __syncthreads();
  if (kh == 0) {
#pragma unroll
    for (int nt = 0; nt < 2; ++nt)
#pragma unroll
      for (int r = 0; r < 16; ++r)
        acc[nt][r] += smem[tile * 2048 + nt * 1024 + r * 64 + l];
  }
  __syncthreads();   // red region dead; ts overlay safe

  // ---- epilogue (kh=0 waves): bias + per-wave LDS transpose + stores ----
  if (kh == 0) {
    const int b = R0 >> 12, i0 = R0 & (LQ - 1);
    float bb[2] = {bq[l & 31], bq[32 + (l & 31)]};
#pragma unroll
    for (int nt = 0; nt < 2; ++nt) {
      float* area = smem + (tile * 2 + nt) * 1088;
#pragma unroll
      for (int r = 0; r < 16; ++r) {
        int io = (r & 3) + 8 * (r >> 2) + 4 * (l >> 5);
        area[(l & 31) * 34 + io] = acc[nt][r] + bb[nt];
      }
      const int e = l & 15, jg = l >> 4;
#pragma unroll
      for (int p = 0; p < 8; ++p) {
        int jj = jg * 8 + p;
        float2 v = *reinterpret_cast<const float2*>(area + jj * 34 + e * 2);
        *reinterpret_cast<float2*>(
            &outp[((size_t)b * DK + nt * 32 + jj) * LQ + i0 + e * 2]) = v;
      }
    }
  }
}

// ---------------------------------------------------------------------------
// Kernel 2 (r9-proven asm form): fused corr+topk, 8 waves.
// MFMA operands are LDS-load-sourced -> compiler waitcnt interlocks; the
// r11-era per-MFMA s_nop fencing removed (pure stall, ~2.2k cyc/wave).
// ---------------------------------------------------------------------------
__global__ __launch_bounds__(512) void corr_topk_kernel(
    const float* __restrict__ qp, const float* __restrict__ kp,
    float* __restrict__ lw) {
  const int row = blockIdx.x;
  const int tid = threadIdx.x;
  __shared__ __align__(16) short qs[3 * 4112 + 4096];  // 32864 B; red overlay
  __shared__ __align__(16) short ks[4096];             // 8192 B
  __shared__ __align__(16) float qf[LQ];               // fp32 for refine
  __shared__ __align__(16) float kf[LQ];
  __shared__ unsigned wk[128];
  __shared__ unsigned scand[CAND];
  __shared__ float rS[CAND];
  __shared__ float ordv[TOPK]; __shared__ int ordl[TOPK];

  const float* qr = qp + ((size_t)row << 12);
  const float* kr = kp + ((size_t)row << 12);

  {
    const float4* q4 = (const float4*)qr;
    float4 v0 = q4[tid * 2], v1 = q4[tid * 2 + 1];
    float4 v2 = q4[(tid * 2 + 2) & 1023];
    ((float4*)qf)[tid * 2] = v0;
    ((float4*)qf)[tid * 2 + 1] = v1;
    float f[12] = {v0.x, v0.y, v0.z, v0.w, v1.x, v1.y, v1.z, v1.w,
                   v2.x, v2.y, v2.z, v2.w};
#pragma unroll
    for (int r = 0; r < 4; ++r) {
      short8v o;
#pragma unroll
      for (int i = 0; i < 8; ++i) o[i] = (short)f2bf(f[i + r]);
      *(short8v*)(&qs[r * 4112 + tid * 8]) = o;
    }
    const float4* k4 = (const float4*)kr;
    float4 w0 = k4[tid * 2], w1 = k4[tid * 2 + 1];
    ((float4*)kf)[tid * 2] = w0;
    ((float4*)kf)[tid * 2 + 1] = w1;
    float g[8] = {w0.x, w0.y, w0.z, w0.w, w1.x, w1.y, w1.z, w1.w};
    int Q = tid;
    int Qs = Q ^ ((Q >> 3) & 7);
    short8v o;
#pragma unroll
    for (int i = 0; i < 8; ++i) o[i] = (short)f2bf(g[i]);
    *(short8v*)(&ks[Qs << 3]) = o;
  }
  __syncthreads();

  const int l = tid & 63, wv = tid >> 6;    // 8 waves
  const int Oq = ((8 * (l >> 5) - 32 * (l & 31)) & 4095) >> 3;
  const int rB = (l & 31) & 3;
  const int Ce = (l & 31) + 8 * (l >> 5) - rB;
  const short* qb = qs + rB * 4112;

  f32x16 acc[4];
#pragma unroll
  for (int M = 0; M < 4; ++M)
#pragma unroll
    for (int i = 0; i < 16; ++i) acc[M][i] = 0.f;

  const int J0 = wv * 32;
#pragma unroll 2
  for (int jb = 0; jb < 32; ++jb) {
    const int J = J0 + jb;
    int e1 = (Ce + 16 * J) & 4095;
    int e2 = (e1 + 4) & 4095;
    uint2 blo = *(const uint2*)(qb + e1);
    uint2 bhi = *(const uint2*)(qb + e2);
    int4 bi; bi.x = blo.x; bi.y = blo.y; bi.z = bhi.x; bi.w = bhi.y;
    short8v bf = __builtin_bit_cast(short8v, bi);
    const int Dq = 2 * J;
#pragma unroll
    for (int M = 0; M < 4; ++M) {
      int Q = (Oq + Dq - 128 * M) & 511;
      Q ^= (Q >> 3) & 7;
      short8v af = *(const short8v*)(&ks[Q << 3]);
      asm volatile("v_mfma_f32_32x32x16_bf16 %0, %1, %2, %0"
                   : "+v"(acc[M]) : "v"(af), "v"(bf));
    }
  }

  mfma_drain();
  __syncthreads();
  float* red = (float*)qs;               // 2 strips x 4096 f32
  const int strip = (wv & 1) * 4096;
  const int ch4 = (l >> 5) * 4, cn = l & 31;
#define RIDX(M, r) (strip + ((M) << 10) + 32 * (((r)&3) + 8 * ((r) >> 2) + ch4) + cn)
  if (wv < 2) {
#pragma unroll
    for (int M = 0; M < 4; ++M)
#pragma unroll
      for (int r = 0; r < 16; ++r) red[RIDX(M, r)] = acc[M][r];
  }
  __syncthreads();
  if (wv >= 2 && wv < 4) {
#pragma unroll
    for (int M = 0; M < 4; ++M)
#pragma unroll
      for (int r = 0; r < 16; ++r) red[RIDX(M, r)] += acc[M][r];
  }
  __syncthreads();
  if (wv >= 4 && wv < 6) {
#pragma unroll
    for (int M = 0; M < 4; ++M)
#pragma unroll
      for (int r = 0; r < 16; ++r) red[RIDX(M, r)] += acc[M][r];
  }
  __syncthreads();
  if (wv >= 6) {
#pragma unroll
    for (int M = 0; M < 4; ++M)
#pragma unroll
      for (int r = 0; r < 16; ++r) red[RIDX(M, r)] += acc[M][r];
  }
  __syncthreads();
#undef RIDX

  {
    unsigned key[8];
#pragma unroll
    for (int i = 0; i < 8; ++i) {
      int tau = wv * 512 + i * 64 + l;
      float v = red[tau] + red[4096 + tau];
      unsigned u = __builtin_bit_cast(unsigned, fabsf(v));
      key[i] = (u & 0xFFFFF000u) | (unsigned)(4095 - tau);
    }
    unsigned bkey = key[0];
#pragma unroll
    for (int i = 1; i < 8; ++i) bkey = key[i] > bkey ? key[i] : bkey;
    for (int round = 0; round < 16; ++round) {
      unsigned m = bkey;
#pragma unroll
      for (int off = 1; off < 64; off <<= 1) {
        unsigned o = __shfl_xor(m, off);
        m = o > m ? o : m;
      }
      if (l == 0) wk[wv * 16 + round] = m;
#pragma unroll
      for (int i = 0; i < 8; ++i) key[i] = (key[i] == m) ? 0u : key[i];
      bkey = key[0];
#pragma unroll
      for (int i = 1; i < 8; ++i) bkey = key[i] > bkey ? key[i] : bkey;
    }
  }
  __syncthreads();

  if (tid < 128) {
    unsigned ki = wk[tid];
    int rank = 0;
    for (int j = 0; j < 128; ++j) rank += (wk[j] > ki);
    if (rank < CAND) scand[rank] = ki;
  }
  __syncthreads();

  {
    const int ci = tid >> 4, sub = tid & 15;
    const int lag = 4095 - (int)(scand[ci] & 0xFFFu);
    float S0 = 0.f, S1 = 0.f, S2 = 0.f, S3 = 0.f;
    for (int it = 0; it < 256; it += 4) {
      int t0 = (it + 0) * 16 + sub, t1 = (it + 1) * 16 + sub;
      int t2 = (it + 2) * 16 + sub, t3 = (it + 3) * 16 + sub;
      S0 = fmaf(kf[t0], qf[(t0 + lag) & 4095], S0);
      S1 = fmaf(kf[t1], qf[(t1 + lag) & 4095], S1);
      S2 = fmaf(kf[t2], qf[(t2 + lag) & 4095], S2);
      S3 = fmaf(kf[t3], qf[(t3 + lag) & 4095], S3);
    }
    float S = (S0 + S1) + (S2 + S3);
    S += __shfl_xor(S, 1);
    S += __shfl_xor(S, 2);
    S += __shfl_xor(S, 4);
    S += __shfl_xor(S, 8);
    if (sub == 0) rS[ci] = S;
  }
  __syncthreads();

  if (tid < CAND) {
    float vi = fabsf(rS[tid]);
    int ii = 4095 - (int)(scand[tid] & 0xFFFu);
    int rank = 0;
    for (int j = 0; j < CAND; ++j) {
      float vj = fabsf(rS[j]);
      int ij = 4095 - (int)(scand[j] & 0xFFFu);
      rank += (vj > vi) || (vj == vi && ij < ii);
    }
    if (rank < TOPK) { ordv[rank] = vi; ordl[rank] = ii; }
  }
  __syncthreads();

  if (tid == 0) {
    float m0 = ordv[0], s = 0.f, e[TOPK];
    for (int k = 0; k < TOPK; ++k) { e[k] = expf(ordv[k] - m0); s += e[k]; }
    float inv = 1.f / s;
    int* ip = (int*)(lw + (size_t)row * 32);
    for (int k = 0; k < TOPK; ++k) {
      ip[k] = ordl[k];
      ((float*)ip)[TOPK + k] = e[k] * inv;
    }
  }
}

// ---------------------------------------------------------------------------
// Kernel 4: aggregation  aggT[row][t] = sum_k w_k * v[row][(t+lag_k)%L]
// ---------------------------------------------------------------------------
__global__ void agg_kernel(const float* __restrict__ vpT,
                           const float* __restrict__ lw,
                           float* __restrict__ aggT) {
  const int row = blockIdx.x, tid = threadIdx.x;
  __shared__ __align__(16) float vr[2 * LQ];
  __shared__ float w[TOPK]; __shared__ int lg[TOPK];

  const float* v0 = vpT + (size_t)row * LQ;
  for (int x = tid; x < LQ; x += 256) {
    float val = v0[x];
    vr[x] = val; vr[x + LQ] = val;
  }
  if (tid < TOPK) {
    lg[tid] = ((const int*)(lw + (size_t)row * 32))[tid];
    w[tid] = lw[(size_t)row * 32 + TOPK + tid];
  }
  __syncthreads();

  float wr[TOPK]; int lr[TOPK];
#pragma unroll
  for (int k = 0; k < TOPK; ++k) { wr[k] = w[k]; lr[k] = lg[k]; }

  for (int m = 0; m < 16; ++m) {
    int t = m * 256 + tid;
    float a = 0.f;
#pragma unroll
    for (int k = 0; k < TOPK; ++k) a = fmaf(wr[k], vr[t + lr[k]], a);
    aggT[(size_t)row * LQ + t] = a;
  }
}

// ---------------------------------------------------------------------------
// Kernel 5: transpose + head-broadcast  out[b][t][c] = aggT[b][c&63][t]
// ---------------------------------------------------------------------------
__global__ void trans_kernel(const float* __restrict__ aggT,
                             float* __restrict__ out) {
  const int b = blockIdx.y;
  const int t0 = blockIdx.x * 64;
  const int tid = threadIdx.x;
  __shared__ float ts[64][65];

#pragma unroll
  for (int v = 0; v < 16; ++v) {
    int f = v * 256 + tid;
    int d = f >> 6, tt = f & 63;
    ts[d][tt] = aggT[((size_t)b * DK + d) * LQ + t0 + tt];
  }
  __syncthreads();

#pragma unroll
  for (int v = 0; v < 128; ++v) {
    int f = v * 256 + tid;
    int tt = f >> 9, c = f & 511;
    out[((size_t)b * LQ + t0 + tt) * (8 * DK) + c] = ts[c & 63][tt];
  }
}

// ---------------------------------------------------------------------------
// ws layout (floats): [0,1M) qp  [1M,2M) kp  [2M,3M) vp
//   [3M,+8K) lw  [4M,5M) aggT  [5M,+32K floats) wpack (128KB)
// ---------------------------------------------------------------------------
extern "C" void kernel_launch(void* const* d_in, const int* in_sizes, int n_in,
                              void* d_out, int out_size, void* d_ws, size_t ws_size,
                              hipStream_t stream) {
  const float* q_in = (const float*)d_in[0];
  const float* k_in = (const float*)d_in[1];
  const float* v_in = (const float*)d_in[2];
  const float* Wq   = (const float*)d_in[3];
  const float* bq   = (const float*)d_in[4];
  float* out = (float*)d_out;
  float* ws  = (float*)d_ws;

  const size_t M = (size_t)NROWS * LQ;        // 1,048,576 floats
  float* qp    = ws;
  float* kp    = ws + M;
  float* vp    = ws + 2 * M;
  float* lw    = ws + 3 * M;
  float* aggT  = ws + 4 * M;
  short* wpack = (short*)(ws + 5 * M);

  wprep_kernel<<<32, 256, 0, stream>>>(Wq, wpack);
  proj_kernel<<<dim3(256, 1, 3), 256, 0, stream>>>(q_in, k_in, v_in, wpack,
                                                   bq, ws);
  corr_topk_kernel<<<NROWS, 512, 0, stream>>>(qp, kp, lw);
  agg_kernel<<<NROWS, 256, 0, stream>>>(vp, lw, aggT);
  trans_kernel<<<dim3(LQ / 64, BQ), 256, 0, stream>>>(aggT, out);
}